// Round 1
// baseline (214.661 us; speedup 1.0000x reference)
//
#include <hip/hip_runtime.h>
#include <math.h>

#define NB 16384
#define NTOK 128
#define NKEY 2662           // 22*11*11
#define NLOG 19
#define TB 32               // batches per workgroup in main kernel

typedef __attribute__((ext_vector_type(8))) short short8;
typedef __attribute__((ext_vector_type(4))) float floatx4;

__device__ __constant__ float c_maxv[22] = {
    9.f, 1.f, 1.f, 10.f, 3.f, 254.f, 1.f, 1.f, 235.f, 8.f, 9.f, 250.f,
    29.f, 1.f, 1.f, 8.f, 1.f, 1.f, 6.f, 3.f, 1.f, 2.f};

__device__ __forceinline__ unsigned short f2bf(float f) {
    unsigned u = __float_as_uint(f);
    return (unsigned short)((u + 0x7FFFu + ((u >> 16) & 1u)) >> 16);  // RNE
}
__device__ __forceinline__ float tanh_fast(float x) {
    float e = __builtin_amdgcn_exp2f(x * 2.885390082f);   // 2*log2(e)
    return 1.f - 2.f * __builtin_amdgcn_rcpf(e + 1.f);
}

// ---------------------------------------------------------------------------
// Precompute 1: G_T[key][v], E2[h][v], h2b, embmean, Wlog, c1wb (bf16)
// ---------------------------------------------------------------------------
__global__ __launch_bounds__(256) void k_pre1(
    const float* __restrict__ w1, const float* __restrict__ b1,
    const float* __restrict__ w2, const float* __restrict__ b2,
    const float* __restrict__ fc1w, const float* __restrict__ encw,
    const float* __restrict__ h0w, const float* __restrict__ h1w,
    const float* __restrict__ a1w, const float* __restrict__ aemb,
    const float* __restrict__ c1w,
    float* __restrict__ G, float* __restrict__ E,
    float* __restrict__ h2b, float* __restrict__ emb,
    float* __restrict__ Wlog, unsigned short* __restrict__ c1wb)
{
    __shared__ float s_w2[72 * 65];       // 18.7 KB: [u_rel*9+k][v] pad-65
    const int bid = blockIdx.x, t = threadIdx.x;
    if (bid < 666) {
        // G_T[key*64+v]; key wave-uniform. w2 staged in LDS in 8 slices of 8 u.
        // Register-prefetch next slice so global loads overlap compute.
        const int v = t & 63;
        const int key_u = __builtin_amdgcn_readfirstlane(bid * 4 + (t >> 6));
        const int key_c = (key_u < NKEY) ? key_u : (NKEY - 1);
        const int c = key_c / 121, rem = key_c % 121, X = rem / 11, Y = rem % 11;

        // incremental (vg,rg) walk for g = t + 256*r: vg=g/72, rg=g%72
        const int vg0 = t / 72, rg0 = t - vg0 * 72;
        const int base0 = vg0 * 576 + rg0;             // w2 idx = base + u0*9

        float rw[18];
        {   // prologue load for slice 0
            int rg = rg0, base = base0;
            #pragma unroll
            for (int r = 0; r < 18; ++r) {
                rw[r] = w2[base];
                rg += 40; base += 1768;
                if (rg >= 72) { rg -= 72; base += 504; }
            }
        }
        float acc = 0.f;
        for (int s = 0; s < 8; ++s) {
            __syncthreads();               // prev compute done, buffer free
            {   // store staged regs -> LDS
                int rg = rg0, vg = vg0;
                #pragma unroll
                for (int r = 0; r < 18; ++r) {
                    s_w2[rg * 65 + vg] = rw[r];
                    rg += 40; vg += 3;
                    if (rg >= 72) { rg -= 72; vg += 1; }
                }
            }
            __syncthreads();               // writes visible
            if (s < 7) {                   // prefetch next slice (overlaps compute)
                int rg = rg0, base = base0 + (s + 1) * 72;
                #pragma unroll
                for (int r = 0; r < 18; ++r) {
                    rw[r] = w2[base];
                    rg += 40; base += 1768;
                    if (rg >= 72) { rg -= 72; base += 504; }
                }
            }
            const int u0 = s * 8;
            #pragma unroll
            for (int ur = 0; ur < 8; ++ur) {
                const int w1base = (u0 + ur) * 550 + c * 25;
                #pragma unroll
                for (int i = 0; i < 3; ++i) {
                    int xi = X - 3 * i;
                    if (xi < 0 || xi > 4) continue;     // wave-uniform branch
                    #pragma unroll
                    for (int j = 0; j < 3; ++j) {
                        int yj = Y - 3 * j;
                        if (yj < 0 || yj > 4) continue; // wave-uniform branch
                        acc += s_w2[(ur * 9 + i * 3 + j) * 65 + v] *
                               w1[w1base + xi * 5 + yj];
                    }
                }
            }
        }
        if (key_u < NKEY) G[key_u * 64 + v] = acc;
    } else if (bid < 698) {
        // E2[h][v] = sum_p enc_w[h,p] * fc1_w[p,v]; h uniform, v = lane
        int m = (bid - 666) * 256 + t;
        int h = __builtin_amdgcn_readfirstlane(m >> 6) & 127;
        int v = t & 63;
        float acc = 0.f;
        #pragma unroll 8
        for (int p = 0; p < 128; ++p)
            acc += encw[h * 128 + p] * fc1w[p * 64 + v];
        E[h * 64 + v] = acc;               // [h][v] layout (for float4 in pre2)
    } else if (bid == 698) {
        // h2b[o] = b2[o] + sum_u b1[u]*sum_k w2[(o*64+u)*9+k]; 4 thr/output
        int o = t >> 2, q = t & 3;
        const float* wp = w2 + (o * 64 + q * 16) * 9;
        float s = 0.f;
        #pragma unroll
        for (int ui = 0; ui < 16; ++ui) {
            float ws = 0.f;
            #pragma unroll
            for (int k = 0; k < 9; ++k) ws += wp[ui * 9 + k];
            s += b1[q * 16 + ui] * ws;
        }
        s += __shfl_xor(s, 1, 64);
        s += __shfl_xor(s, 2, 64);
        if (q == 0) h2b[o] = s + b2[o];
    } else if (bid == 699) {
        // emb[e] = mean_r aemb[r][e]; 4 thr/output
        if (t < 64) {
            int e = t & 15, rq = t >> 4;
            float s = 0.f;
            #pragma unroll
            for (int rr = 0; rr < 25; ++rr) s += aemb[(rq * 25 + rr) * 16 + e];
            s += __shfl_xor(s, 16, 64);
            s += __shfl_xor(s, 32, 64);
            if (t < 16) emb[e] = s * 0.01f;
        }
    } else if (bid < 710) {
        // Wlog[o][h] = sum_{a<512} headW[o][a] * actor1_w[a][h]
        int n = (bid - 700) * 256 + t;
        if (n < NLOG * 128) {
            int o = __builtin_amdgcn_readfirstlane(n >> 7);
            int h = n & 127;
            const float* hw = (o < 9) ? (h0w + o * 528) : (h1w + (o - 9) * 528);
            float acc = 0.f;
            #pragma unroll 8
            for (int a = 0; a < 512; ++a)
                acc += hw[a] * a1w[a * 128 + h];
            Wlog[n] = acc;
        }
    } else {
        // bf16 copy of critic weights, same [j][k] layout (B^T for MFMA)
        int n = (bid - 710) * 256 + t;     // 131072 exact, 512 blocks
        c1wb[n] = f2bf(c1w[n]);
    }
}

// ---------------------------------------------------------------------------
// Precompute 2: Weff[key][h] (1/MAX folded), b_eff, blog
// ---------------------------------------------------------------------------
__global__ __launch_bounds__(256) void k_pre2(
    const float* __restrict__ G, const float* __restrict__ E,
    const float* __restrict__ h2b, const float* __restrict__ emb,
    const float* __restrict__ fc1w, const float* __restrict__ fc1b,
    const float* __restrict__ encw, const float* __restrict__ encb,
    const float* __restrict__ a1b,
    const float* __restrict__ h0w, const float* __restrict__ h0b,
    const float* __restrict__ h1w, const float* __restrict__ h1b,
    float* __restrict__ Weff, float* __restrict__ beff, float* __restrict__ blog)
{
    __shared__ float s_h2[64];
    __shared__ float s_t[128];
    const int bid = blockIdx.x, t = threadIdx.x;
    if (bid < 1331) {
        int n = bid * 256 + t;            // 340736 exact
        int key = __builtin_amdgcn_readfirstlane(n >> 7);
        int h = n & 127;
        const float4* E4 = (const float4*)E;           // E2[h*64+v]
        const float4* G4 = (const float4*)(G + key * 64);  // uniform -> s_load
        float acc = 0.f;
        #pragma unroll
        for (int vq = 0; vq < 16; ++vq) {
            float4 e = E4[h * 16 + vq];
            float4 g = G4[vq];
            acc += e.x * g.x + e.y * g.y + e.z * g.z + e.w * g.w;
        }
        Weff[n] = acc / c_maxv[key / 121];
    } else {
        if (t < 64) s_h2[t] = h2b[t];
        __syncthreads();
        if (t < 128) {
            // tmp[p] = fc1b[p] + fc1w[p]·h2b
            const float4* f4 = (const float4*)(fc1w + t * 64);
            float s = fc1b[t];
            #pragma unroll
            for (int vq = 0; vq < 16; ++vq) {
                float4 w = f4[vq];
                s += w.x * s_h2[vq * 4]     + w.y * s_h2[vq * 4 + 1] +
                     w.z * s_h2[vq * 4 + 2] + w.w * s_h2[vq * 4 + 3];
            }
            s_t[t] = s;
        } else {
            // blog: 8 lanes per output, 2 passes of 16 outputs
            int tp = t - 128;
            int os = tp >> 3, ai = tp & 7;
            #pragma unroll
            for (int rep = 0; rep < 2; ++rep) {
                int o = os + rep * 16;
                int oc = (o < NLOG) ? o : (NLOG - 1);
                const float* hw = (oc < 9) ? (h0w + oc * 528)
                                           : (h1w + (oc - 9) * 528);
                float s = 0.f;
                for (int a = ai; a < 528; a += 8) {
                    float m = (a < 512) ? a1b[a] : emb[a - 512];
                    s += hw[a] * m;
                }
                s += __shfl_xor(s, 1, 64);
                s += __shfl_xor(s, 2, 64);
                s += __shfl_xor(s, 4, 64);
                if (ai == 0 && o < NLOG)
                    blog[o] = s + ((o < 9) ? h0b[o] : h1b[o - 9]);
            }
        }
        __syncthreads();
        if (t < 128) {
            const float4* e4 = (const float4*)(encw + t * 128);
            float s = encb[t];
            #pragma unroll
            for (int pq = 0; pq < 32; ++pq) {
                float4 w = e4[pq];
                s += w.x * s_t[pq * 4]     + w.y * s_t[pq * 4 + 1] +
                     w.z * s_t[pq * 4 + 2] + w.w * s_t[pq * 4 + 3];
            }
            beff[t] = s;
        }
    }
}

// ---------------------------------------------------------------------------
// Main fused kernel. 512 threads, TB=32 batches/WG, grid = 512.
// Phase C: two M=16 MFMA tiles share every B-fragment load (halves L2 traffic
// for the 256 KB critic matrix vs TB=16).
// ---------------------------------------------------------------------------
__global__ __launch_bounds__(512, 4) void k_main(
    const int* __restrict__ obs,
    const float* __restrict__ Weff, const float* __restrict__ beff,
    const unsigned short* __restrict__ c1wb, const float* __restrict__ c1b,
    const float* __restrict__ vw, const float* __restrict__ vb,
    const float* __restrict__ Wlog, const float* __restrict__ blog,
    float* __restrict__ out)
{
    __shared__ int            s_lst[TB * 32];      // 4 KB packed token list
    __shared__ float          s_hidden[TB * 128];  // 16 KB fp32 (for logits)
    __shared__ unsigned short s_hb[TB * 136];      // 8.5 KB bf16, pad 136
    __shared__ int            s_cnt[TB];
    __shared__ float          s_val[8 * 32];

    const int tid = threadIdx.x, bid = blockIdx.x;
    const int b0 = bid * TB;

    if (tid < TB) s_cnt[tid] = 0;
    __syncthreads();

    // ---- Phase A: decode + append valid tokens (pack m<<20|val<<12|key) ----
    // int4-vectorized: 3 x int4 = 4 tokens per thread per iteration.
    {
        const int gtok0 = b0 * NTOK;
        #pragma unroll
        for (int k = 0; k < TB * NTOK / (512 * 4); ++k) {   // 2 iterations
            int g = tid + 512 * k;                          // token-quad index
            const int4* p = (const int4*)(obs + (size_t)(gtok0 + 4 * g) * 3);
            int4 A = p[0], Bv = p[1], Cv = p[2];
            int d[12] = {A.x, A.y, A.z, A.w, Bv.x, Bv.y, Bv.z, Bv.w,
                         Cv.x, Cv.y, Cv.z, Cv.w};
            #pragma unroll
            for (int s = 0; s < 4; ++s) {
                int o0 = d[3 * s], o1 = d[3 * s + 1], o2 = d[3 * s + 2];
                o0 = (o0 == 255) ? 0 : o0;          // per-component 255 masking
                o1 = (o1 == 255) ? 0 : o1;
                o2 = (o2 == 255) ? 0 : o2;
                int x = (o0 >> 4) & 15, y = o0 & 15;
                if (x < 11 && y < 11 && o1 < 22) {
                    int tt = 4 * g + s;
                    int bb = tt >> 7, m = tt & 127;
                    int pos = atomicAdd(&s_cnt[bb], 1);
                    if (pos < 32)
                        s_lst[bb * 32 + pos] =
                            (m << 20) | (o2 << 12) | (o1 * 121 + x * 11 + y);
                }
            }
        }
    }
    __syncthreads();

    // ---- Phase A2: last-write-wins dedupe on the tiny list ----
    {
        int bb = tid >> 4, e0 = tid & 15;
        int n = s_cnt[bb]; if (n > 32) n = 32;
        #pragma unroll
        for (int r = 0; r < 2; ++r) {
            int e = e0 + 16 * r;
            if (e < n) {
                int p = s_lst[bb * 32 + e];
                bool dead = false;
                for (int i = 0; i < n; ++i) {
                    int q = s_lst[bb * 32 + i];
                    dead |= (((q ^ p) & 0xFFF) == 0) && (q > p);
                }
                if (dead) s_lst[bb * 32 + e] = p & ~0x000FF000;  // val := 0
            }
        }
    }
    __syncthreads();

    // ---- Phase B: hidden[b][h] = b_eff[h] + sum val * Weff[key][h] ----
    // dual-stream: two batches in flight per 128-thread group (2x MLP on the
    // serial L2-gather chain).
    {
        int h = tid & 127, bg = tid >> 7;              // 4 groups of 128
        float be = beff[h];
        #pragma unroll
        for (int it = 0; it < 4; ++it) {
            int bbA = bg + it * 8, bbB = bbA + 4;
            int nA = s_cnt[bbA]; if (nA > 32) nA = 32;
            int nB = s_cnt[bbB]; if (nB > 32) nB = 32;
            int nm = (nA > nB) ? nA : nB;
            float aA = be, aB = be;
            for (int i = 0; i < nm; ++i) {
                if (i < nA) {
                    int p = s_lst[bbA * 32 + i];
                    aA += (float)((p >> 12) & 0xFF) * Weff[(p & 0xFFF) * 128 + h];
                }
                if (i < nB) {
                    int p = s_lst[bbB * 32 + i];
                    aB += (float)((p >> 12) & 0xFF) * Weff[(p & 0xFFF) * 128 + h];
                }
            }
            s_hidden[bbA * 128 + h] = aA; s_hb[bbA * 136 + h] = f2bf(aA);
            s_hidden[bbB * 128 + h] = aB; s_hb[bbB * 136 + h] = f2bf(aB);
        }
    }
    __syncthreads();

    // ---- Phase C: value = sum_j tanh(hidden @ c1w.T + b)_j * vw_j (MFMA) ----
    // 8 waves x 128 columns each; each bf load feeds 2 MFMAs (2 M-tiles).
    {
        const int lane = tid & 63, w = tid >> 6;
        const int lm = lane & 15, quad = lane >> 4;
        short8 af0[4], af1[4];
        #pragma unroll
        for (int kk = 0; kk < 4; ++kk) {
            af0[kk] = *(const short8*)&s_hb[lm * 136 + kk * 32 + quad * 8];
            af1[kk] = *(const short8*)&s_hb[(16 + lm) * 136 + kk * 32 + quad * 8];
        }
        float vp0[4] = {0.f, 0.f, 0.f, 0.f}, vp1[4] = {0.f, 0.f, 0.f, 0.f};
        for (int nt = 0; nt < 8; ++nt) {
            int j = w * 128 + nt * 16 + lm;
            const short8* cp = (const short8*)&c1wb[j * 128];
            floatx4 a0 = {0.f, 0.f, 0.f, 0.f}, a1 = {0.f, 0.f, 0.f, 0.f};
            #pragma unroll
            for (int kk = 0; kk < 4; ++kk) {
                short8 bf = cp[kk * 4 + quad];   // c1wb[j*128 + kk*32 + quad*8]
                a0 = __builtin_amdgcn_mfma_f32_16x16x32_bf16(af0[kk], bf, a0, 0, 0, 0);
                a1 = __builtin_amdgcn_mfma_f32_16x16x32_bf16(af1[kk], bf, a1, 0, 0, 0);
            }
            float bj = c1b[j], wj = vw[j];
            #pragma unroll
            for (int r = 0; r < 4; ++r) {
                vp0[r] += tanh_fast(a0[r] + bj) * wj;
                vp1[r] += tanh_fast(a1[r] + bj) * wj;
            }
        }
        #pragma unroll
        for (int off = 1; off <= 8; off <<= 1) {
            #pragma unroll
            for (int r = 0; r < 4; ++r) {
                vp0[r] += __shfl_xor(vp0[r], off, 64);
                vp1[r] += __shfl_xor(vp1[r], off, 64);
            }
        }
        if (lm == 0) {
            #pragma unroll
            for (int r = 0; r < 4; ++r) {
                s_val[w * 32 + quad * 4 + r]      = vp0[r];
                s_val[w * 32 + 16 + quad * 4 + r] = vp1[r];
            }
        }
    }
    __syncthreads();
    if (tid < TB) {
        float v = 0.f;
        #pragma unroll
        for (int w = 0; w < 8; ++w) v += s_val[w * 32 + tid];
        out[NB * NLOG + b0 + tid] = v + vb[0];
    }

    // ---- Phase D: logits[b][o] = blog[o] + hidden[b]·Wlog[o]  (fp32) ----
    {
        const float4* s_h4 = (const float4*)s_hidden;
        const float4* wl4  = (const float4*)Wlog;
        int bl = tid >> 4, oo = tid & 15;              // 32 batches x 16 lanes
        #pragma unroll
        for (int rep = 0; rep < 2; ++rep) {
            int o = oo + rep * 16;
            if (o < NLOG) {
                float acc = blog[o];
                #pragma unroll
                for (int hq = 0; hq < 32; ++hq) {
                    float4 hv = s_h4[bl * 32 + hq];
                    float4 wl = wl4[o * 32 + hq];
                    acc += wl.x * hv.x + wl.y * hv.y + wl.z * hv.z + wl.w * hv.w;
                }
                out[(b0 + bl) * NLOG + o] = acc;
            }
        }
    }
}

// ---------------------------------------------------------------------------
extern "C" void kernel_launch(void* const* d_in, const int* in_sizes, int n_in,
                              void* d_out, int out_size, void* d_ws, size_t ws_size,
                              hipStream_t stream)
{
    const int*   obs  = (const int*)  d_in[0];
    const float* w1   = (const float*)d_in[1];
    const float* b1   = (const float*)d_in[2];
    const float* w2   = (const float*)d_in[3];
    const float* b2   = (const float*)d_in[4];
    const float* fc1w = (const float*)d_in[5];
    const float* fc1b = (const float*)d_in[6];
    const float* encw = (const float*)d_in[7];
    const float* encb = (const float*)d_in[8];
    const float* c1w  = (const float*)d_in[9];
    const float* c1b  = (const float*)d_in[10];
    const float* vw   = (const float*)d_in[11];
    const float* vb   = (const float*)d_in[12];
    const float* a1w  = (const float*)d_in[13];
    const float* a1b  = (const float*)d_in[14];
    const float* aemb = (const float*)d_in[15];
    const float* h0w  = (const float*)d_in[16];
    const float* h0b  = (const float*)d_in[17];
    const float* h1w  = (const float*)d_in[18];
    const float* h1b  = (const float*)d_in[19];

    float* W    = (float*)d_ws;
    float* G    = W;                 // 170368  (G_T[key][v])
    float* E    = W + 170368;        // 8192    (E2[h][v])
    float* h2b  = W + 178560;        // 64
    float* emb  = W + 178624;        // 16
    float* Weff = W + 178640;        // 340736
    float* beff = W + 519376;        // 128
    float* Wlog = W + 519504;        // 2432
    float* blog = W + 521936;        // 19
    unsigned short* c1wb = (unsigned short*)(W + 524288);  // 131072 ushort

    hipLaunchKernelGGL(k_pre1, dim3(1222), dim3(256), 0, stream,
                       w1, b1, w2, b2, fc1w, encw, h0w, h1w, a1w, aemb, c1w,
                       G, E, h2b, emb, Wlog, c1wb);
    hipLaunchKernelGGL(k_pre2, dim3(1332), dim3(256), 0, stream,
                       G, E, h2b, emb, fc1w, fc1b, encw, encb, a1b,
                       h0w, h0b, h1w, h1b, Weff, beff, blog);
    hipLaunchKernelGGL(k_main, dim3(NB / TB), dim3(512), 0, stream,
                       obs, Weff, beff, c1wb, c1b, vw, vb, Wlog, blog,
                       (float*)d_out);
}

// Round 2
// 187.791 us; speedup vs baseline: 1.1431x; 1.1431x over previous
//
#include <hip/hip_runtime.h>
#include <math.h>

#define NB 16384
#define NTOK 128
#define NKEY 2662           // 22*11*11
#define NLOG 19
#define TB 32               // batches per workgroup in main kernel

typedef __attribute__((ext_vector_type(8))) short short8;
typedef __attribute__((ext_vector_type(4))) float floatx4;

__device__ __constant__ float c_maxv[22] = {
    9.f, 1.f, 1.f, 10.f, 3.f, 254.f, 1.f, 1.f, 235.f, 8.f, 9.f, 250.f,
    29.f, 1.f, 1.f, 8.f, 1.f, 1.f, 6.f, 3.f, 1.f, 2.f};

__device__ __forceinline__ unsigned short f2bf(float f) {
    unsigned u = __float_as_uint(f);
    return (unsigned short)((u + 0x7FFFu + ((u >> 16) & 1u)) >> 16);  // RNE
}
__device__ __forceinline__ float tanh_fast(float x) {
    float e = __builtin_amdgcn_exp2f(x * 2.885390082f);   // 2*log2(e)
    return 1.f - 2.f * __builtin_amdgcn_rcpf(e + 1.f);
}

// ---------------------------------------------------------------------------
// Single precompute kernel (773 blocks):
//   [0,666)    G_T[key][v] with 1/MAX folded   (r0-proven staging form)
//   [666,698)  E_T[v*128+h] = enc_w @ fc1_w
//   698        tail chain: h2b -> tmp/emb -> beff/blog (one block, synced)
//   [699,709)  Wlog[o][h]
//   [709,773)  c1wb bf16 copy (ushort8 vectorized)
// ---------------------------------------------------------------------------
__global__ __launch_bounds__(256) void k_pre(
    const float* __restrict__ w1, const float* __restrict__ b1,
    const float* __restrict__ w2, const float* __restrict__ b2,
    const float* __restrict__ fc1w, const float* __restrict__ fc1b,
    const float* __restrict__ encw, const float* __restrict__ encb,
    const float* __restrict__ a1w, const float* __restrict__ a1b,
    const float* __restrict__ aemb,
    const float* __restrict__ h0w, const float* __restrict__ h0b,
    const float* __restrict__ h1w, const float* __restrict__ h1b,
    const float* __restrict__ c1w,
    float* __restrict__ G, float* __restrict__ E,
    float* __restrict__ beff, float* __restrict__ Wlog,
    float* __restrict__ blog, unsigned short* __restrict__ c1wb)
{
    __shared__ float s_w2[72 * 65];       // 18.7 KB: [u_rel*9+k][v] pad-65
    __shared__ float s_h2[64];
    __shared__ float s_t[128];
    __shared__ float s_emb[16];
    const int bid = blockIdx.x, t = threadIdx.x;
    if (bid < 666) {
        // G_T[key*64+v]; key wave-uniform, w2 staged in LDS, w1 scalar loads
        const int v = t & 63;
        const int key_u = __builtin_amdgcn_readfirstlane(bid * 4 + (t >> 6));
        const int key_c = (key_u < NKEY) ? key_u : (NKEY - 1);
        const int c = key_c / 121, rem = key_c % 121, X = rem / 11, Y = rem % 11;
        float acc = 0.f;
        for (int u0 = 0; u0 < 64; u0 += 8) {
            __syncthreads();
            // stage w2[v][u0..u0+7][k] -> s_w2 as [rem72][v]
            #pragma unroll
            for (int r = 0; r < 18; ++r) {
                int g = t + 256 * r;              // 4608 elements
                int vg = g / 72, rg = g % 72;
                s_w2[rg * 65 + vg] = w2[vg * 576 + u0 * 9 + rg];
            }
            __syncthreads();
            #pragma unroll
            for (int ur = 0; ur < 8; ++ur) {
                const int w1base = (u0 + ur) * 550 + c * 25;
                #pragma unroll
                for (int i = 0; i < 3; ++i) {
                    int xi = X - 3 * i;
                    if (xi < 0 || xi > 4) continue;     // wave-uniform branch
                    #pragma unroll
                    for (int j = 0; j < 3; ++j) {
                        int yj = Y - 3 * j;
                        if (yj < 0 || yj > 4) continue; // wave-uniform branch
                        acc += s_w2[(ur * 9 + i * 3 + j) * 65 + v] *
                               w1[w1base + xi * 5 + yj];
                    }
                }
            }
        }
        if (key_u < NKEY) G[key_u * 64 + v] = acc / c_maxv[c];  // fold 1/MAX
    } else if (bid < 698) {
        // E_T[v*128+h] = sum_p enc_w[h,p] * fc1_w[p,v]; h uniform, v = lane
        int m = (bid - 666) * 256 + t;
        int h = __builtin_amdgcn_readfirstlane(m >> 6) & 127;
        int v = t & 63;
        float acc = 0.f;
        #pragma unroll 8
        for (int p = 0; p < 128; ++p)
            acc += encw[h * 128 + p] * fc1w[p * 64 + v];
        E[v * 128 + h] = acc;
    } else if (bid == 698) {
        // stage 1: h2b[o] = b2[o] + sum_u b1[u]*sum_k w2[(o*64+u)*9+k]
        {
            int o = t >> 2, q = t & 3;
            const float* wp = w2 + (o * 64 + q * 16) * 9;
            float s = 0.f;
            #pragma unroll
            for (int ui = 0; ui < 16; ++ui) {
                float ws = 0.f;
                #pragma unroll
                for (int k = 0; k < 9; ++k) ws += wp[ui * 9 + k];
                s += b1[q * 16 + ui] * ws;
            }
            s += __shfl_xor(s, 1, 64);
            s += __shfl_xor(s, 2, 64);
            if (q == 0) s_h2[o] = s + b2[o];
        }
        __syncthreads();
        // stage 2: tmp[p] (t<128) | emb (t in [128,192))
        if (t < 128) {
            const float4* f4 = (const float4*)(fc1w + t * 64);
            float s = fc1b[t];
            #pragma unroll
            for (int vq = 0; vq < 16; ++vq) {
                float4 w = f4[vq];
                s += w.x * s_h2[vq * 4]     + w.y * s_h2[vq * 4 + 1] +
                     w.z * s_h2[vq * 4 + 2] + w.w * s_h2[vq * 4 + 3];
            }
            s_t[t] = s;
        } else if (t < 192) {
            int lane = t & 63;
            int e = lane & 15, rq = lane >> 4;
            float s = 0.f;
            #pragma unroll
            for (int rr = 0; rr < 25; ++rr) s += aemb[(rq * 25 + rr) * 16 + e];
            s += __shfl_xor(s, 16, 64);
            s += __shfl_xor(s, 32, 64);
            if (lane < 16) s_emb[e] = s * 0.01f;
        }
        __syncthreads();
        // stage 3: beff (t<128) | blog (t>=128)
        if (t < 128) {
            const float4* e4 = (const float4*)(encw + t * 128);
            float s = encb[t];
            #pragma unroll
            for (int pq = 0; pq < 32; ++pq) {
                float4 w = e4[pq];
                s += w.x * s_t[pq * 4]     + w.y * s_t[pq * 4 + 1] +
                     w.z * s_t[pq * 4 + 2] + w.w * s_t[pq * 4 + 3];
            }
            beff[t] = s;
        } else {
            int tp = t - 128;
            int os = tp >> 3, ai = tp & 7;
            #pragma unroll
            for (int rep = 0; rep < 2; ++rep) {
                int o = os + rep * 16;
                int oc = (o < NLOG) ? o : (NLOG - 1);
                const float* hw = (oc < 9) ? (h0w + oc * 528)
                                           : (h1w + (oc - 9) * 528);
                float s = 0.f;
                for (int a = ai; a < 528; a += 8) {
                    float m = (a < 512) ? a1b[a] : s_emb[a - 512];
                    s += hw[a] * m;
                }
                s += __shfl_xor(s, 1, 64);
                s += __shfl_xor(s, 2, 64);
                s += __shfl_xor(s, 4, 64);
                if (ai == 0 && o < NLOG)
                    blog[o] = s + ((o < 9) ? h0b[o] : h1b[o - 9]);
            }
        }
    } else if (bid < 709) {
        // Wlog[o][h] = sum_{a<512} headW[o][a] * actor1_w[a][h]
        int n = (bid - 699) * 256 + t;
        if (n < NLOG * 128) {
            int o = __builtin_amdgcn_readfirstlane(n >> 7);
            int h = n & 127;
            const float* hw = (o < 9) ? (h0w + o * 528) : (h1w + (o - 9) * 528);
            float acc = 0.f;
            #pragma unroll 8
            for (int a = 0; a < 512; ++a)
                acc += hw[a] * a1w[a * 128 + h];
            Wlog[n] = acc;
        }
    } else {
        // bf16 copy of critic weights, ushort8-vectorized (64 blocks)
        int n = ((bid - 709) * 256 + t) * 8;        // 131072 total
        float4 a = *(const float4*)(c1w + n);
        float4 b4 = *(const float4*)(c1w + n + 4);
        short8 r;
        r[0] = (short)f2bf(a.x);  r[1] = (short)f2bf(a.y);
        r[2] = (short)f2bf(a.z);  r[3] = (short)f2bf(a.w);
        r[4] = (short)f2bf(b4.x); r[5] = (short)f2bf(b4.y);
        r[6] = (short)f2bf(b4.z); r[7] = (short)f2bf(b4.w);
        *(short8*)(c1wb + n) = r;
    }
}

// ---------------------------------------------------------------------------
// Main fused kernel. 512 threads, TB=32 batches/WG, grid = 512.
// Phase B factored: x64[v] = sum val*G[key][v] (256B token gathers, in regs),
// then hidden = beff + E^T x64 via LDS GEMV (E staged under phase A).
// ---------------------------------------------------------------------------
__global__ __launch_bounds__(512, 4) void k_main(
    const int* __restrict__ obs,
    const float* __restrict__ G, const float* __restrict__ E,
    const float* __restrict__ beff,
    const unsigned short* __restrict__ c1wb, const float* __restrict__ c1b,
    const float* __restrict__ vw, const float* __restrict__ vb,
    const float* __restrict__ Wlog, const float* __restrict__ blog,
    float* __restrict__ out)
{
    __shared__ int            s_lst[TB * 32];      // 4 KB packed token list
    __shared__ float          s_hidden[TB * 128];  // 16 KB fp32 (for logits)
    __shared__ unsigned short s_hb[TB * 136];      // 8.5 KB bf16, pad 136
    __shared__ float          s_x[TB * 64];        // 8 KB x64 vectors
    __shared__ float          s_E[8192];           // 32 KB staged E_T[v][h]
    __shared__ int            s_cnt[TB];
    __shared__ float          s_val[8 * 32];

    const int tid = threadIdx.x, bid = blockIdx.x;
    const int b0 = bid * TB;

    // issue E stage loads first; they complete under phase A processing
    const float4* E4g = (const float4*)E;
    float4 e0 = E4g[tid], e1 = E4g[tid + 512],
           e2 = E4g[tid + 1024], e3 = E4g[tid + 1536];

    if (tid < TB) s_cnt[tid] = 0;
    __syncthreads();

    // ---- Phase A: decode + append valid tokens (pack m<<20|val<<12|key) ----
    {
        const int gtok0 = b0 * NTOK;
        #pragma unroll
        for (int k = 0; k < TB * NTOK / (512 * 4); ++k) {   // 2 iterations
            int g = tid + 512 * k;                          // token-quad index
            const int4* p = (const int4*)(obs + (size_t)(gtok0 + 4 * g) * 3);
            int4 A = p[0], Bv = p[1], Cv = p[2];
            int d[12] = {A.x, A.y, A.z, A.w, Bv.x, Bv.y, Bv.z, Bv.w,
                         Cv.x, Cv.y, Cv.z, Cv.w};
            #pragma unroll
            for (int s = 0; s < 4; ++s) {
                int o0 = d[3 * s], o1 = d[3 * s + 1], o2 = d[3 * s + 2];
                o0 = (o0 == 255) ? 0 : o0;          // per-component 255 masking
                o1 = (o1 == 255) ? 0 : o1;
                o2 = (o2 == 255) ? 0 : o2;
                int x = (o0 >> 4) & 15, y = o0 & 15;
                if (x < 11 && y < 11 && o1 < 22) {
                    int tt = 4 * g + s;
                    int bb = tt >> 7, m = tt & 127;
                    int pos = atomicAdd(&s_cnt[bb], 1);
                    if (pos < 32)
                        s_lst[bb * 32 + pos] =
                            (m << 20) | (o2 << 12) | (o1 * 121 + x * 11 + y);
                }
            }
        }
        // complete the E staging
        float4* sE4 = (float4*)s_E;
        sE4[tid] = e0; sE4[tid + 512] = e1;
        sE4[tid + 1024] = e2; sE4[tid + 1536] = e3;
    }
    __syncthreads();

    // ---- Phase A2: last-write-wins dedupe on the tiny list ----
    {
        int bb = tid >> 4, e0i = tid & 15;
        int n = s_cnt[bb]; if (n > 32) n = 32;
        #pragma unroll
        for (int r = 0; r < 2; ++r) {
            int e = e0i + 16 * r;
            if (e < n) {
                int p = s_lst[bb * 32 + e];
                bool dead = false;
                for (int i = 0; i < n; ++i) {
                    int q = s_lst[bb * 32 + i];
                    dead |= (((q ^ p) & 0xFFF) == 0) && (q > p);
                }
                if (dead) s_lst[bb * 32 + e] = p & ~0x000FF000;  // val := 0
            }
        }
    }
    __syncthreads();

    // ---- Phase B1: x[bb][v] = sum val * G[key][v]; wave w owns bb w*4..+3 --
    // gathers are 256B coalesced rows, dual-stream, acc in registers.
    {
        int w = tid >> 6, lane = tid & 63;
        #pragma unroll
        for (int jp = 0; jp < 2; ++jp) {
            int bbA = w * 4 + jp * 2, bbB = bbA + 1;
            int nA = s_cnt[bbA]; if (nA > 32) nA = 32;
            int nB = s_cnt[bbB]; if (nB > 32) nB = 32;
            int nm = (nA > nB) ? nA : nB;
            float aA = 0.f, aB = 0.f;
            for (int i = 0; i < nm; ++i) {
                if (i < nA) {
                    int p = s_lst[bbA * 32 + i];
                    aA += (float)((p >> 12) & 0xFF) * G[(p & 0xFFF) * 64 + lane];
                }
                if (i < nB) {
                    int p = s_lst[bbB * 32 + i];
                    aB += (float)((p >> 12) & 0xFF) * G[(p & 0xFFF) * 64 + lane];
                }
            }
            s_x[bbA * 64 + lane] = aA;
            s_x[bbB * 64 + lane] = aB;
        }
    }
    __syncthreads();

    // ---- Phase B2: hidden[bb][h] = beff[h] + sum_v x[bb][v]*E[v][h] -------
    // group g (128 thr) owns 8 batches; loop-interchange reuses each E read
    // across all 8 accumulators; x read as b128 broadcasts.
    {
        int g = tid >> 7, h = tid & 127;
        float be = beff[h];
        float acc[8];
        #pragma unroll
        for (int b = 0; b < 8; ++b) acc[b] = be;
        const float4* x4 = (const float4*)s_x;
        #pragma unroll
        for (int vq = 0; vq < 16; ++vq) {
            float ev0 = s_E[(vq * 4 + 0) * 128 + h];
            float ev1 = s_E[(vq * 4 + 1) * 128 + h];
            float ev2 = s_E[(vq * 4 + 2) * 128 + h];
            float ev3 = s_E[(vq * 4 + 3) * 128 + h];
            #pragma unroll
            for (int b = 0; b < 8; ++b) {
                float4 xv = x4[(g * 8 + b) * 16 + vq];
                acc[b] += xv.x * ev0 + xv.y * ev1 + xv.z * ev2 + xv.w * ev3;
            }
        }
        #pragma unroll
        for (int b = 0; b < 8; ++b) {
            int bb = g * 8 + b;
            s_hidden[bb * 128 + h] = acc[b];
            s_hb[bb * 136 + h] = f2bf(acc[b]);
        }
    }
    __syncthreads();

    // ---- Phase C: value = sum_j tanh(hidden @ c1w.T + b)_j * vw_j (MFMA) ----
    {
        const int lane = tid & 63, w = tid >> 6;
        const int lm = lane & 15, quad = lane >> 4;
        short8 af0[4], af1[4];
        #pragma unroll
        for (int kk = 0; kk < 4; ++kk) {
            af0[kk] = *(const short8*)&s_hb[lm * 136 + kk * 32 + quad * 8];
            af1[kk] = *(const short8*)&s_hb[(16 + lm) * 136 + kk * 32 + quad * 8];
        }
        float vp0[4] = {0.f, 0.f, 0.f, 0.f}, vp1[4] = {0.f, 0.f, 0.f, 0.f};
        for (int nt = 0; nt < 8; ++nt) {
            int j = w * 128 + nt * 16 + lm;
            const short8* cp = (const short8*)&c1wb[j * 128];
            floatx4 a0 = {0.f, 0.f, 0.f, 0.f}, a1 = {0.f, 0.f, 0.f, 0.f};
            #pragma unroll
            for (int kk = 0; kk < 4; ++kk) {
                short8 bf = cp[kk * 4 + quad];
                a0 = __builtin_amdgcn_mfma_f32_16x16x32_bf16(af0[kk], bf, a0, 0, 0, 0);
                a1 = __builtin_amdgcn_mfma_f32_16x16x32_bf16(af1[kk], bf, a1, 0, 0, 0);
            }
            float bj = c1b[j], wj = vw[j];
            #pragma unroll
            for (int r = 0; r < 4; ++r) {
                vp0[r] += tanh_fast(a0[r] + bj) * wj;
                vp1[r] += tanh_fast(a1[r] + bj) * wj;
            }
        }
        #pragma unroll
        for (int off = 1; off <= 8; off <<= 1) {
            #pragma unroll
            for (int r = 0; r < 4; ++r) {
                vp0[r] += __shfl_xor(vp0[r], off, 64);
                vp1[r] += __shfl_xor(vp1[r], off, 64);
            }
        }
        if (lm == 0) {
            #pragma unroll
            for (int r = 0; r < 4; ++r) {
                s_val[w * 32 + quad * 4 + r]      = vp0[r];
                s_val[w * 32 + 16 + quad * 4 + r] = vp1[r];
            }
        }
    }

    // ---- Phase D: logits (fp32) — independent of s_val, runs pre-barrier --
    {
        const float4* s_h4 = (const float4*)s_hidden;
        const float4* wl4  = (const float4*)Wlog;
        int bl = tid >> 4, oo = tid & 15;              // 32 batches x 16 lanes
        #pragma unroll
        for (int rep = 0; rep < 2; ++rep) {
            int o = oo + rep * 16;
            if (o < NLOG) {
                float acc = blog[o];
                #pragma unroll
                for (int hq = 0; hq < 32; ++hq) {
                    float4 hv = s_h4[bl * 32 + hq];
                    float4 wl = wl4[o * 32 + hq];
                    acc += wl.x * hv.x + wl.y * hv.y + wl.z * hv.z + wl.w * hv.w;
                }
                out[(b0 + bl) * NLOG + o] = acc;
            }
        }
    }
    __syncthreads();
    if (tid < TB) {
        float v = 0.f;
        #pragma unroll
        for (int w = 0; w < 8; ++w) v += s_val[w * 32 + tid];
        out[NB * NLOG + b0 + tid] = v + vb[0];
    }
}

// ---------------------------------------------------------------------------
extern "C" void kernel_launch(void* const* d_in, const int* in_sizes, int n_in,
                              void* d_out, int out_size, void* d_ws, size_t ws_size,
                              hipStream_t stream)
{
    const int*   obs  = (const int*)  d_in[0];
    const float* w1   = (const float*)d_in[1];
    const float* b1   = (const float*)d_in[2];
    const float* w2   = (const float*)d_in[3];
    const float* b2   = (const float*)d_in[4];
    const float* fc1w = (const float*)d_in[5];
    const float* fc1b = (const float*)d_in[6];
    const float* encw = (const float*)d_in[7];
    const float* encb = (const float*)d_in[8];
    const float* c1w  = (const float*)d_in[9];
    const float* c1b  = (const float*)d_in[10];
    const float* vw   = (const float*)d_in[11];
    const float* vb   = (const float*)d_in[12];
    const float* a1w  = (const float*)d_in[13];
    const float* a1b  = (const float*)d_in[14];
    const float* aemb = (const float*)d_in[15];
    const float* h0w  = (const float*)d_in[16];
    const float* h0b  = (const float*)d_in[17];
    const float* h1w  = (const float*)d_in[18];
    const float* h1b  = (const float*)d_in[19];

    float* W    = (float*)d_ws;
    float* G    = W;                 // 170368  (G_T[key][v], 1/MAX folded)
    float* E    = W + 170368;        // 8192    (E_T[v][h])
    float* beff = W + 178560;        // 128
    float* Wlog = W + 178688;        // 2432
    float* blog = W + 181120;        // 32 (19 used)
    unsigned short* c1wb = (unsigned short*)(W + 181152);  // 131072 ushort

    hipLaunchKernelGGL(k_pre, dim3(773), dim3(256), 0, stream,
                       w1, b1, w2, b2, fc1w, fc1b, encw, encb, a1w, a1b, aemb,
                       h0w, h0b, h1w, h1b, c1w,
                       G, E, beff, Wlog, blog, c1wb);
    hipLaunchKernelGGL(k_main, dim3(NB / TB), dim3(512), 0, stream,
                       obs, G, E, beff, c1wb, c1b, vw, vb, Wlog, blog,
                       (float*)d_out);
}